// Round 1
// baseline (941.835 us; speedup 1.0000x reference)
//
#include <hip/hip_runtime.h>

#define NN 8192
#define DD 256
#define EE 262144

typedef __attribute__((ext_vector_type(8))) short bf16x8;
typedef __attribute__((ext_vector_type(4))) float f32x4;

// f32 -> bf16 round-to-nearest-even
static __device__ __forceinline__ unsigned short f2b(float x) {
  unsigned int u = __float_as_uint(x);
  u += 0x7fffu + ((u >> 16) & 1u);
  return (unsigned short)(u >> 16);
}

// ---------------- CSR build ----------------
__global__ void k_count(const int* __restrict__ dst, int* __restrict__ cnt) {
  int e = blockIdx.x * 256 + threadIdx.x;
  if (e < EE) atomicAdd(&cnt[dst[e]], 1);
}

__global__ void k_scan(const int* __restrict__ cnt, int* __restrict__ row_ptr) {
  __shared__ int s[1024];
  int t = threadIdx.x;
  int loc[8]; int tot = 0;
#pragma unroll
  for (int i = 0; i < 8; ++i) { loc[i] = cnt[t * 8 + i]; tot += loc[i]; }
  s[t] = tot; __syncthreads();
  for (int off = 1; off < 1024; off <<= 1) {
    int v = s[t];
    int add = (t >= off) ? s[t - off] : 0;
    __syncthreads();
    s[t] = v + add;
    __syncthreads();
  }
  int run = (t == 0) ? 0 : s[t - 1];
#pragma unroll
  for (int i = 0; i < 8; ++i) { row_ptr[t * 8 + i] = run; run += loc[i]; }
  if (t == 1023) row_ptr[NN] = run;
}

__global__ void k_fill(const int* __restrict__ dst, const int* __restrict__ row_ptr,
                       int* __restrict__ fill, int* __restrict__ elist) {
  int e = blockIdx.x * 256 + threadIdx.x;
  if (e < EE) {
    int d = dst[e];
    int idx = atomicAdd(&fill[d], 1);
    elist[row_ptr[d] + idx] = e;
  }
}

// ---------------- SimpleConv (mean aggr + cat root) -> bf16 [N,2D] ----------------
__global__ void k_conv(const float* __restrict__ x, const int* __restrict__ src,
                       const float* __restrict__ w, const int* __restrict__ row_ptr,
                       const int* __restrict__ elist, const int* __restrict__ cnt,
                       unsigned short* __restrict__ out) {
  int n = blockIdx.x, d = threadIdx.x;
  float acc = 0.f;
  int b = row_ptr[n], e2 = row_ptr[n + 1];
  for (int i = b; i < e2; ++i) {
    int e = elist[i];
    acc += x[(size_t)src[e] * DD + d] * w[e];
  }
  acc *= 1.0f / fmaxf((float)cnt[n], 1.0f);
  out[(size_t)n * 512 + d]       = f2b(x[(size_t)n * DD + d]);
  out[(size_t)n * 512 + 256 + d] = f2b(acc);
}

// ---------------- shared MFMA GEMM core: 128x128 tile, 4 waves (2x2), BK=64 ----------------
// A [M,K] row-major bf16, BT [N,K] row-major bf16 (B pre-transposed).
// LDS tiles [128][64] shorts with 16B-slot XOR swizzle (slot ^= row&7).
static __device__ __forceinline__ void gemm_core(const unsigned short* __restrict__ A,
                                                 const unsigned short* __restrict__ BT,
                                                 int K, int m0, int n0,
                                                 unsigned short* As, unsigned short* Bs,
                                                 f32x4 acc[4][4]) {
  const int tid = threadIdx.x;
  const int lane = tid & 63, wid = tid >> 6;
  const int wr = wid >> 1, wc = wid & 1;
  const int r16 = lane & 15, g = lane >> 4;
  for (int kt = 0; kt < K; kt += 64) {
    __syncthreads();
#pragma unroll
    for (int j = 0; j < 4; ++j) {
      int c = tid + j * 256;          // 0..1023 chunks of 16B
      int row = c >> 3, slot = c & 7;
      int sw = (slot ^ (row & 7)) << 3;
      *(bf16x8*)&As[row * 64 + sw] = *(const bf16x8*)&A[(size_t)(m0 + row) * K + kt + slot * 8];
      *(bf16x8*)&Bs[row * 64 + sw] = *(const bf16x8*)&BT[(size_t)(n0 + row) * K + kt + slot * 8];
    }
    __syncthreads();
#pragma unroll
    for (int kk = 0; kk < 64; kk += 32) {
      bf16x8 av[4], bv[4];
      int bslot = (kk >> 3) + g;      // 16B slot within the 128B row
#pragma unroll
      for (int m = 0; m < 4; ++m) {
        int row = wr * 64 + m * 16 + r16;
        av[m] = *(const bf16x8*)&As[row * 64 + ((bslot ^ (row & 7)) << 3)];
      }
#pragma unroll
      for (int n2 = 0; n2 < 4; ++n2) {
        int row = wc * 64 + n2 * 16 + r16;
        bv[n2] = *(const bf16x8*)&Bs[row * 64 + ((bslot ^ (row & 7)) << 3)];
      }
#pragma unroll
      for (int m = 0; m < 4; ++m)
#pragma unroll
        for (int n2 = 0; n2 < 4; ++n2)
          acc[m][n2] = __builtin_amdgcn_mfma_f32_16x16x32_bf16(av[m], bv[n2], acc[m][n2], 0, 0, 0);
    }
  }
}

template <bool RELU, bool RESID, bool WB>
__global__ __launch_bounds__(256) void k_gemm(const unsigned short* __restrict__ A,
                                              const unsigned short* __restrict__ BT,
                                              const float* __restrict__ bias,
                                              const float* __restrict__ resid,
                                              float* __restrict__ C,
                                              unsigned short* __restrict__ Cb,
                                              int K, int Ncols) {
  __shared__ unsigned short As[128 * 64];
  __shared__ unsigned short Bs[128 * 64];
  f32x4 acc[4][4] = {};
  int m0 = blockIdx.x * 128, n0 = blockIdx.y * 128;
  gemm_core(A, BT, K, m0, n0, As, Bs, acc);
  const int tid = threadIdx.x;
  const int lane = tid & 63, wid = tid >> 6;
  const int wr = wid >> 1, wc = wid & 1;
  const int r16 = lane & 15, g = lane >> 4;
#pragma unroll
  for (int m = 0; m < 4; ++m)
#pragma unroll
    for (int rr = 0; rr < 4; ++rr) {
      int grow = m0 + wr * 64 + m * 16 + g * 4 + rr;
#pragma unroll
      for (int n2 = 0; n2 < 4; ++n2) {
        int gcol = n0 + wc * 64 + n2 * 16 + r16;
        float v = acc[m][n2][rr] + bias[gcol];
        if (RELU) v = fmaxf(v, 0.f);
        if (RESID) v += resid[(size_t)grow * Ncols + gcol];
        C[(size_t)grow * Ncols + gcol] = v;
        if (WB) Cb[(size_t)grow * Ncols + gcol] = f2b(v);
      }
    }
}

// logits = Zl @ Zl^T, fused softplus(l) - l*ADJ mean-reduction (never materialized)
__global__ __launch_bounds__(256) void k_logits(const unsigned short* __restrict__ Zl,
                                                const float* __restrict__ ADJ,
                                                double* __restrict__ gl_sum) {
  __shared__ unsigned short As[128 * 64];
  __shared__ unsigned short Bs[128 * 64];
  f32x4 acc[4][4] = {};
  int m0 = blockIdx.x * 128, n0 = blockIdx.y * 128;
  gemm_core(Zl, Zl, 256, m0, n0, As, Bs, acc);
  const int tid = threadIdx.x;
  const int lane = tid & 63, wid = tid >> 6;
  const int wr = wid >> 1, wc = wid & 1;
  const int r16 = lane & 15, g = lane >> 4;
  float lsum = 0.f;
#pragma unroll
  for (int m = 0; m < 4; ++m)
#pragma unroll
    for (int rr = 0; rr < 4; ++rr) {
      int grow = m0 + wr * 64 + m * 16 + g * 4 + rr;
#pragma unroll
      for (int n2 = 0; n2 < 4; ++n2) {
        int gcol = n0 + wc * 64 + n2 * 16 + r16;
        float c = acc[m][n2][rr];
        float adj = ADJ[(size_t)grow * NN + gcol];
        float sp = fmaxf(c, 0.f) + log1pf(expf(-fabsf(c)));  // stable softplus
        lsum += sp - c * adj;
      }
    }
  __syncthreads();
  float* red = (float*)As;
  red[tid] = lsum;
  __syncthreads();
  for (int off = 128; off > 0; off >>= 1) {
    if (tid < off) red[tid] += red[tid + off];
    __syncthreads();
  }
  if (tid == 0) atomicAdd(gl_sum, (double)red[0]);
}

// ---------------- Z / Z_l / KL ----------------
__global__ void k_z(const float* __restrict__ mulv, const float* __restrict__ eps,
                    float* __restrict__ Zout, unsigned short* __restrict__ Zl,
                    double* __restrict__ kl_sum) {
  int n = blockIdx.x, d = threadIdx.x;
  float mu = mulv[(size_t)n * 512 + d];
  float lv = mulv[(size_t)n * 512 + 256 + d];
  float sig = expf(0.5f * lv);
  float es = 0.f;
#pragma unroll
  for (int k = 0; k < 8; ++k) {
    size_t idx = ((size_t)n * 8 + k) * 256 + d;
    float e = eps[idx];
    Zout[idx] = mu + e * sig;
    es += e;
  }
  Zl[(size_t)n * 256 + d] = f2b(mu + sig * es * 0.125f);
  float t = 1.0f + lv - mu * mu - sig * sig;  // sig^2 == exp(lv)
  __shared__ float red[256];
  red[d] = t;
  __syncthreads();
  for (int off = 128; off > 0; off >>= 1) {
    if (d < off) red[d] += red[d + off];
    __syncthreads();
  }
  if (d == 0) atomicAdd(kl_sum, (double)red[0]);
}

// ---------------- weight prep: bf16 + transpose to [N][K] ----------------
__global__ void k_prep(const float* __restrict__ W1, const float* __restrict__ W2,
                       const float* __restrict__ W3, const float* __restrict__ W4,
                       const float* __restrict__ b3, const float* __restrict__ b4,
                       unsigned short* __restrict__ W1t, unsigned short* __restrict__ W2t,
                       unsigned short* __restrict__ W34t, float* __restrict__ b34) {
  int idx = blockIdx.x * 256 + threadIdx.x;  // 131072 threads
  if (idx < 512 * 256) {                     // W1/W2: [512][256] -> [256][512]
    int k = idx >> 8, n = idx & 255;
    W1t[n * 512 + k] = f2b(W1[idx]);
    W2t[n * 512 + k] = f2b(W2[idx]);
  }
  if (idx < 256 * 512) {                     // W3|W4: [256][256]x2 -> [512][256]
    int k = idx >> 9, n = idx & 511;
    float v = (n < 256) ? W3[k * 256 + n] : W4[k * 256 + (n - 256)];
    W34t[n * 256 + k] = f2b(v);
  }
  if (idx < 512) b34[idx] = (idx < 256) ? b3[idx] : b4[idx - 256];
}

__global__ void k_final(const double* __restrict__ sums, float* __restrict__ out) {
  double kl = -0.5 * sums[0] / (double)NN;
  double gl = sums[1] / ((double)NN * (double)NN);
  out[0] = (float)(kl + gl);
}

// ---------------- launch ----------------
extern "C" void kernel_launch(void* const* d_in, const int* in_sizes, int n_in,
                              void* d_out, int out_size, void* d_ws, size_t ws_size,
                              hipStream_t stream) {
  const float* enc = (const float*)d_in[0];
  const int*   ei  = (const int*)d_in[1];
  const int*   src = ei;
  const int*   dst = ei + EE;
  const float* w   = (const float*)d_in[2];
  const float* ADJ = (const float*)d_in[3];
  const float* eps = (const float*)d_in[4];
  const float* W1  = (const float*)d_in[5];
  const float* b1  = (const float*)d_in[6];
  const float* W2  = (const float*)d_in[7];
  const float* b2  = (const float*)d_in[8];
  const float* W3  = (const float*)d_in[9];
  const float* b3  = (const float*)d_in[10];
  const float* W4  = (const float*)d_in[11];
  const float* b4  = (const float*)d_in[12];

  char* ws = (char*)d_ws;
  size_t off = 0;
  auto alloc = [&](size_t bytes) -> void* {
    void* p = ws + off;
    off = (off + bytes + 255) & ~(size_t)255;
    return p;
  };
  unsigned short* h1b   = (unsigned short*)alloc((size_t)NN * 512 * 2);  // conv out (both convs)
  float*          h     = (float*)alloc((size_t)NN * 256 * 4);           // gemm1 out
  float*          mulv  = (float*)alloc((size_t)NN * 512 * 4);           // [mu | lv]
  unsigned short* enc2b = (unsigned short*)alloc((size_t)NN * 256 * 2);
  unsigned short* Zlb   = (unsigned short*)alloc((size_t)NN * 256 * 2);
  unsigned short* W1t   = (unsigned short*)alloc(512 * 256 * 2);
  unsigned short* W2t   = (unsigned short*)alloc(512 * 256 * 2);
  unsigned short* W34t  = (unsigned short*)alloc(512 * 256 * 2);
  float*          b34v  = (float*)alloc(512 * 4);
  int*            cnt   = (int*)alloc(NN * 4);
  int*            row_ptr = (int*)alloc((NN + 1) * 4);
  int*            fill  = (int*)alloc(NN * 4);
  int*            elist = (int*)alloc((size_t)EE * 4);
  double*         sums  = (double*)alloc(16);  // [0]=kl_sum, [1]=gl_sum

  float* out_enc2 = (float*)d_out;
  float* out_Z    = out_enc2 + (size_t)NN * 256;
  float* out_loss = out_Z + (size_t)NN * 8 * 256;

  hipMemsetAsync(cnt, 0, NN * 4, stream);
  hipMemsetAsync(fill, 0, NN * 4, stream);
  hipMemsetAsync(sums, 0, 16, stream);

  k_prep<<<512, 256, 0, stream>>>(W1, W2, W3, W4, b3, b4, W1t, W2t, W34t, b34v);
  k_count<<<EE / 256, 256, 0, stream>>>(dst, cnt);
  k_scan<<<1, 1024, 0, stream>>>(cnt, row_ptr);
  k_fill<<<EE / 256, 256, 0, stream>>>(dst, row_ptr, fill, elist);

  // conv1 + block1
  k_conv<<<NN, 256, 0, stream>>>(enc, src, w, row_ptr, elist, cnt, h1b);
  k_gemm<true, false, false><<<dim3(64, 2), 256, 0, stream>>>(h1b, W1t, b1, nullptr, h, nullptr, 512, 256);
  // conv2 + block2 (+ residual enc), also emit bf16 enc2
  k_conv<<<NN, 256, 0, stream>>>(h, src, w, row_ptr, elist, cnt, h1b);
  k_gemm<true, true, true><<<dim3(64, 2), 256, 0, stream>>>(h1b, W2t, b2, enc, out_enc2, enc2b, 512, 256);
  // mu|lv fused GEMM
  k_gemm<false, false, false><<<dim3(64, 4), 256, 0, stream>>>(enc2b, W34t, b34v, nullptr, mulv, nullptr, 256, 512);
  // Z, Z_l, KL
  k_z<<<NN, 256, 0, stream>>>(mulv, eps, out_Z, Zlb, sums);
  // logits GEMM + BCE reduce
  k_logits<<<dim3(64, 64), 256, 0, stream>>>(Zlb, ADJ, sums + 1);
  k_final<<<1, 1, 0, stream>>>(sums, out_loss);
}

// Round 3
// 659.036 us; speedup vs baseline: 1.4291x; 1.4291x over previous
//
#include <hip/hip_runtime.h>

#define NN 8192
#define DD 256
#define EE 262144

typedef __attribute__((ext_vector_type(8))) short bf16x8;
typedef __attribute__((ext_vector_type(4))) float f32x4;

// f32 -> bf16 round-to-nearest-even
static __device__ __forceinline__ unsigned short f2b(float x) {
  unsigned int u = __float_as_uint(x);
  u += 0x7fffu + ((u >> 16) & 1u);
  return (unsigned short)(u >> 16);
}
static __device__ __forceinline__ float b2f(unsigned short u) {
  return __uint_as_float(((unsigned int)u) << 16);
}

// ---------------- CSR build ----------------
__global__ void k_count(const int* __restrict__ dst, int* __restrict__ cnt) {
  int e = blockIdx.x * 256 + threadIdx.x;
  if (e < EE) atomicAdd(&cnt[dst[e]], 1);
}

__global__ void k_scan(const int* __restrict__ cnt, int* __restrict__ row_ptr) {
  __shared__ int s[1024];
  int t = threadIdx.x;
  int loc[8]; int tot = 0;
#pragma unroll
  for (int i = 0; i < 8; ++i) { loc[i] = cnt[t * 8 + i]; tot += loc[i]; }
  s[t] = tot; __syncthreads();
  for (int off = 1; off < 1024; off <<= 1) {
    int v = s[t];
    int add = (t >= off) ? s[t - off] : 0;
    __syncthreads();
    s[t] = v + add;
    __syncthreads();
  }
  int run = (t == 0) ? 0 : s[t - 1];
#pragma unroll
  for (int i = 0; i < 8; ++i) { row_ptr[t * 8 + i] = run; run += loc[i]; }
  if (t == 1023) row_ptr[NN] = run;
}

// pack (src, w) per CSR slot: removes the elist->src/w indirection in conv
__global__ void k_fill(const int* __restrict__ dst, const int* __restrict__ src,
                       const float* __restrict__ w, const int* __restrict__ row_ptr,
                       int* __restrict__ fill, int* __restrict__ slist,
                       float* __restrict__ wlist) {
  int e = blockIdx.x * 256 + threadIdx.x;
  if (e < EE) {
    int d = dst[e];
    int idx = atomicAdd(&fill[d], 1);
    int pos = row_ptr[d] + idx;
    slist[pos] = src[e];
    wlist[pos] = w[e];
  }
}

// ---------------- SimpleConv: bf16 gather, wave-per-node, mean aggr + cat root ----------------
__global__ __launch_bounds__(256) void k_conv(const unsigned short* __restrict__ xb,
                                              const int* __restrict__ slist,
                                              const float* __restrict__ wlist,
                                              const int* __restrict__ row_ptr,
                                              unsigned short* __restrict__ out) {
  int tid = threadIdx.x, wid = tid >> 6, lane = tid & 63;
  int n = blockIdx.x * 4 + wid;
  const ushort4* x4 = (const ushort4*)xb;  // row = 64 x ushort4
  float ax = 0.f, ay = 0.f, az = 0.f, aw = 0.f;
  int b = row_ptr[n], e2 = row_ptr[n + 1];
  int i = b;
  for (; i + 1 < e2; i += 2) {
    int s0 = slist[i], s1 = slist[i + 1];
    float w0 = wlist[i], w1 = wlist[i + 1];
    ushort4 v0 = x4[(size_t)s0 * 64 + lane];
    ushort4 v1 = x4[(size_t)s1 * 64 + lane];
    ax += b2f(v0.x) * w0 + b2f(v1.x) * w1;
    ay += b2f(v0.y) * w0 + b2f(v1.y) * w1;
    az += b2f(v0.z) * w0 + b2f(v1.z) * w1;
    aw += b2f(v0.w) * w0 + b2f(v1.w) * w1;
  }
  if (i < e2) {
    int s0 = slist[i];
    float w0 = wlist[i];
    ushort4 v0 = x4[(size_t)s0 * 64 + lane];
    ax += b2f(v0.x) * w0; ay += b2f(v0.y) * w0;
    az += b2f(v0.z) * w0; aw += b2f(v0.w) * w0;
  }
  float inv = 1.0f / fmaxf((float)(e2 - b), 1.0f);
  ushort4 rv = x4[(size_t)n * 64 + lane];
  ushort4 av;
  av.x = f2b(ax * inv); av.y = f2b(ay * inv);
  av.z = f2b(az * inv); av.w = f2b(aw * inv);
  *(ushort4*)&out[(size_t)n * 512 + lane * 4]       = rv;
  *(ushort4*)&out[(size_t)n * 512 + 256 + lane * 4] = av;
}

// ---------------- shared MFMA GEMM core: 128x128 tile, 4 waves (2x2), BK=64 ----------------
static __device__ __forceinline__ void gemm_core(const unsigned short* __restrict__ A,
                                                 const unsigned short* __restrict__ BT,
                                                 int K, int m0, int n0,
                                                 unsigned short* As, unsigned short* Bs,
                                                 f32x4 acc[4][4]) {
  const int tid = threadIdx.x;
  const int lane = tid & 63, wid = tid >> 6;
  const int wr = wid >> 1, wc = wid & 1;
  const int r16 = lane & 15, g = lane >> 4;
  for (int kt = 0; kt < K; kt += 64) {
    __syncthreads();
#pragma unroll
    for (int j = 0; j < 4; ++j) {
      int c = tid + j * 256;          // 0..1023 chunks of 16B
      int row = c >> 3, slot = c & 7;
      int sw = (slot ^ (row & 7)) << 3;
      *(bf16x8*)&As[row * 64 + sw] = *(const bf16x8*)&A[(size_t)(m0 + row) * K + kt + slot * 8];
      *(bf16x8*)&Bs[row * 64 + sw] = *(const bf16x8*)&BT[(size_t)(n0 + row) * K + kt + slot * 8];
    }
    __syncthreads();
#pragma unroll
    for (int kk = 0; kk < 64; kk += 32) {
      bf16x8 av[4], bv[4];
      int bslot = (kk >> 3) + g;
#pragma unroll
      for (int m = 0; m < 4; ++m) {
        int row = wr * 64 + m * 16 + r16;
        av[m] = *(const bf16x8*)&As[row * 64 + ((bslot ^ (row & 7)) << 3)];
      }
#pragma unroll
      for (int n2 = 0; n2 < 4; ++n2) {
        int row = wc * 64 + n2 * 16 + r16;
        bv[n2] = *(const bf16x8*)&Bs[row * 64 + ((bslot ^ (row & 7)) << 3)];
      }
#pragma unroll
      for (int m = 0; m < 4; ++m)
#pragma unroll
        for (int n2 = 0; n2 < 4; ++n2)
          acc[m][n2] = __builtin_amdgcn_mfma_f32_16x16x32_bf16(av[m], bv[n2], acc[m][n2], 0, 0, 0);
    }
  }
}

template <bool RELU, bool RESID, bool WC, bool WB>
__global__ __launch_bounds__(256) void k_gemm(const unsigned short* __restrict__ A,
                                              const unsigned short* __restrict__ BT,
                                              const float* __restrict__ bias,
                                              const float* __restrict__ resid,
                                              float* __restrict__ C,
                                              unsigned short* __restrict__ Cb,
                                              int K, int Ncols) {
  __shared__ unsigned short As[128 * 64];
  __shared__ unsigned short Bs[128 * 64];
  f32x4 acc[4][4] = {};
  int m0 = blockIdx.x * 128, n0 = blockIdx.y * 128;
  gemm_core(A, BT, K, m0, n0, As, Bs, acc);
  const int tid = threadIdx.x;
  const int lane = tid & 63, wid = tid >> 6;
  const int wr = wid >> 1, wc = wid & 1;
  const int r16 = lane & 15, g = lane >> 4;
#pragma unroll
  for (int m = 0; m < 4; ++m)
#pragma unroll
    for (int rr = 0; rr < 4; ++rr) {
      int grow = m0 + wr * 64 + m * 16 + g * 4 + rr;
#pragma unroll
      for (int n2 = 0; n2 < 4; ++n2) {
        int gcol = n0 + wc * 64 + n2 * 16 + r16;
        float v = acc[m][n2][rr] + bias[gcol];
        if (RELU) v = fmaxf(v, 0.f);
        if (RESID) v += resid[(size_t)grow * Ncols + gcol];
        if (WC) C[(size_t)grow * Ncols + gcol] = v;
        if (WB) Cb[(size_t)grow * Ncols + gcol] = f2b(v);
      }
    }
}

// ---------------- softplus term: Sum sp(l_ij) over symmetric l = Zl Zl^T ----------------
// l is bitwise-symmetric, so only by>=bx blocks run; off-diagonal weight 2. No ADJ read.
__global__ __launch_bounds__(256) void k_logits(const unsigned short* __restrict__ Zl,
                                                double* __restrict__ sp_sum) {
  int bx = blockIdx.x, by = blockIdx.y;
  if (by < bx) return;
  __shared__ unsigned short As[128 * 64];
  __shared__ unsigned short Bs[128 * 64];
  f32x4 acc[4][4] = {};
  int m0 = bx * 128, n0 = by * 128;
  gemm_core(Zl, Zl, 256, m0, n0, As, Bs, acc);
  const int tid = threadIdx.x;
  float wgt = (bx == by) ? 1.0f : 2.0f;
  float lsum = 0.f;
#pragma unroll
  for (int m = 0; m < 4; ++m)
#pragma unroll
    for (int rr = 0; rr < 4; ++rr)
#pragma unroll
      for (int n2 = 0; n2 < 4; ++n2) {
        float c = acc[m][n2][rr];
        // fast stable softplus: max(c,0) + log(1 + exp(-|c|)) via HW exp/log
        lsum += fmaxf(c, 0.f) + __logf(1.0f + __expf(-fabsf(c)));
      }
  lsum *= wgt;
  __syncthreads();
  float* red = (float*)As;
  red[tid] = lsum;
  __syncthreads();
  for (int off = 128; off > 0; off >>= 1) {
    if (tid < off) red[tid] += red[tid + off];
    __syncthreads();
  }
  if (tid == 0) atomicAdd(sp_sum, (double)red[0]);
}

// ---------------- adj term: Sum_{adj_ij != 0} adj_ij * (zl_i . zl_j) ----------------
// ADJ is ~0/1 with ~32 nnz/row: stream ADJ coalesced (wave per row), ballot-compact
// nonzeros, wave-cooperatively accumulate s_i += adj_ij * zl_j, then one dot zl_i.s_i.
__global__ __launch_bounds__(256) void k_adj(const float* __restrict__ ADJ,
                                             const unsigned short* __restrict__ Zl,
                                             double* __restrict__ dot_sum) {
  int tid = threadIdx.x, wid = tid >> 6, lane = tid & 63;
  int i = blockIdx.x * 4 + wid;
  const ushort4* z4 = (const ushort4*)Zl;
  ushort4 ziv = z4[(size_t)i * 64 + lane];
  float zx = b2f(ziv.x), zy = b2f(ziv.y), zz = b2f(ziv.z), zw = b2f(ziv.w);
  float sx = 0.f, sy = 0.f, sz = 0.f, sw = 0.f;
  const float4* a4 = (const float4*)(ADJ + (size_t)i * NN);
#pragma unroll 1
  for (int c0 = 0; c0 < 32; ++c0) {
    float4 a = a4[c0 * 64 + lane];
    bool any = (a.x != 0.f) | (a.y != 0.f) | (a.z != 0.f) | (a.w != 0.f);
    unsigned long long m = __ballot(any);
    while (m) {
      int l = __ffsll((long long)m) - 1;
      m &= m - 1;
      float axx = __shfl(a.x, l), ayy = __shfl(a.y, l);
      float azz = __shfl(a.z, l), aww = __shfl(a.w, l);
      int jb = c0 * 256 + l * 4;
      if (axx != 0.f) {
        ushort4 v = z4[(size_t)(jb + 0) * 64 + lane];
        sx += axx * b2f(v.x); sy += axx * b2f(v.y); sz += axx * b2f(v.z); sw += axx * b2f(v.w);
      }
      if (ayy != 0.f) {
        ushort4 v = z4[(size_t)(jb + 1) * 64 + lane];
        sx += ayy * b2f(v.x); sy += ayy * b2f(v.y); sz += ayy * b2f(v.z); sw += ayy * b2f(v.w);
      }
      if (azz != 0.f) {
        ushort4 v = z4[(size_t)(jb + 2) * 64 + lane];
        sx += azz * b2f(v.x); sy += azz * b2f(v.y); sz += azz * b2f(v.z); sw += azz * b2f(v.w);
      }
      if (aww != 0.f) {
        ushort4 v = z4[(size_t)(jb + 3) * 64 + lane];
        sx += aww * b2f(v.x); sy += aww * b2f(v.y); sz += aww * b2f(v.z); sw += aww * b2f(v.w);
      }
    }
  }
  float t = zx * sx + zy * sy + zz * sz + zw * sw;
#pragma unroll
  for (int off = 32; off > 0; off >>= 1) t += __shfl_down(t, off, 64);
  __shared__ float red[4];
  if (lane == 0) red[wid] = t;
  __syncthreads();
  if (tid == 0) atomicAdd(dot_sum, (double)(red[0] + red[1] + red[2] + red[3]));
}

// ---------------- Z / Z_l / KL : wave-per-node, float4 ----------------
__global__ __launch_bounds__(256) void k_z(const float* __restrict__ mulv,
                                           const float* __restrict__ eps,
                                           float* __restrict__ Zout,
                                           unsigned short* __restrict__ Zl,
                                           double* __restrict__ kl_sum) {
  int tid = threadIdx.x, wid = tid >> 6, lane = tid & 63;
  int n = blockIdx.x * 4 + wid;
  const float4* m4 = (const float4*)mulv;   // row = 128 x float4: [mu(64) | lv(64)]
  float4 mu = m4[(size_t)n * 128 + lane];
  float4 lv = m4[(size_t)n * 128 + 64 + lane];
  float4 sig;
  sig.x = __expf(0.5f * lv.x); sig.y = __expf(0.5f * lv.y);
  sig.z = __expf(0.5f * lv.z); sig.w = __expf(0.5f * lv.w);
  const float4* e4 = (const float4*)eps;
  float4* z4 = (float4*)Zout;
  float esx = 0.f, esy = 0.f, esz = 0.f, esw = 0.f;
#pragma unroll
  for (int k = 0; k < 8; ++k) {
    size_t idx = ((size_t)n * 8 + k) * 64 + lane;
    float4 e = e4[idx];
    float4 z;
    z.x = mu.x + e.x * sig.x; z.y = mu.y + e.y * sig.y;
    z.z = mu.z + e.z * sig.z; z.w = mu.w + e.w * sig.w;
    z4[idx] = z;
    esx += e.x; esy += e.y; esz += e.z; esw += e.w;
  }
  ushort4 zl;
  zl.x = f2b(mu.x + sig.x * esx * 0.125f);
  zl.y = f2b(mu.y + sig.y * esy * 0.125f);
  zl.z = f2b(mu.z + sig.z * esz * 0.125f);
  zl.w = f2b(mu.w + sig.w * esw * 0.125f);
  *(ushort4*)&Zl[(size_t)n * 256 + lane * 4] = zl;
  float t = (1.0f + lv.x - mu.x * mu.x - sig.x * sig.x)
          + (1.0f + lv.y - mu.y * mu.y - sig.y * sig.y)
          + (1.0f + lv.z - mu.z * mu.z - sig.z * sig.z)
          + (1.0f + lv.w - mu.w * mu.w - sig.w * sig.w);
#pragma unroll
  for (int off = 32; off > 0; off >>= 1) t += __shfl_down(t, off, 64);
  __shared__ float red[4];
  if (lane == 0) red[wid] = t;
  __syncthreads();
  if (tid == 0) atomicAdd(kl_sum, (double)(red[0] + red[1] + red[2] + red[3]));
}

// ---------------- prep: weights bf16+transpose, enc -> bf16 ----------------
__global__ void k_prep(const float* __restrict__ enc,
                       const float* __restrict__ W1, const float* __restrict__ W2,
                       const float* __restrict__ W3, const float* __restrict__ W4,
                       const float* __restrict__ b3, const float* __restrict__ b4,
                       unsigned short* __restrict__ encb,
                       unsigned short* __restrict__ W1t, unsigned short* __restrict__ W2t,
                       unsigned short* __restrict__ W34t, float* __restrict__ b34) {
  int idx = blockIdx.x * 256 + threadIdx.x;  // 524288 threads
  {  // enc cast: 2M floats as 524288 float4
    float4 v = ((const float4*)enc)[idx];
    ushort4 o;
    o.x = f2b(v.x); o.y = f2b(v.y); o.z = f2b(v.z); o.w = f2b(v.w);
    ((ushort4*)encb)[idx] = o;
  }
  if (idx < 512 * 256) {                     // W1/W2: [512][256] -> [256][512]
    int k = idx >> 8, n = idx & 255;
    W1t[n * 512 + k] = f2b(W1[idx]);
    W2t[n * 512 + k] = f2b(W2[idx]);
  }
  if (idx < 256 * 512) {                     // W3|W4: [256][256]x2 -> [512][256]
    int k = idx >> 9, n = idx & 511;
    float v = (n < 256) ? W3[k * 256 + n] : W4[k * 256 + (n - 256)];
    W34t[n * 256 + k] = f2b(v);
  }
  if (idx < 512) b34[idx] = (idx < 256) ? b3[idx] : b4[idx - 256];
}

__global__ void k_final(const double* __restrict__ sums, float* __restrict__ out) {
  double kl = -0.5 * sums[0] / (double)NN;
  double gl = (sums[1] - sums[2]) / ((double)NN * (double)NN);
  out[0] = (float)(kl + gl);
}

// ---------------- launch ----------------
extern "C" void kernel_launch(void* const* d_in, const int* in_sizes, int n_in,
                              void* d_out, int out_size, void* d_ws, size_t ws_size,
                              hipStream_t stream) {
  const float* enc = (const float*)d_in[0];
  const int*   ei  = (const int*)d_in[1];
  const int*   src = ei;
  const int*   dst = ei + EE;
  const float* w   = (const float*)d_in[2];
  const float* ADJ = (const float*)d_in[3];
  const float* eps = (const float*)d_in[4];
  const float* W1  = (const float*)d_in[5];
  const float* b1  = (const float*)d_in[6];
  const float* W2  = (const float*)d_in[7];
  const float* b2  = (const float*)d_in[8];
  const float* W3  = (const float*)d_in[9];
  const float* b3  = (const float*)d_in[10];
  const float* W4  = (const float*)d_in[11];
  const float* b4  = (const float*)d_in[12];

  char* ws = (char*)d_ws;
  size_t off = 0;
  auto alloc = [&](size_t bytes) -> void* {
    void* p = ws + off;
    off = (off + bytes + 255) & ~(size_t)255;
    return p;
  };
  unsigned short* h1b   = (unsigned short*)alloc((size_t)NN * 512 * 2);  // conv out (both convs)
  unsigned short* hb    = (unsigned short*)alloc((size_t)NN * 256 * 2);  // gemm1 out (bf16 only)
  float*          mulv  = (float*)alloc((size_t)NN * 512 * 4);           // [mu | lv]
  unsigned short* enc2b = (unsigned short*)alloc((size_t)NN * 256 * 2);
  unsigned short* Zlb   = (unsigned short*)alloc((size_t)NN * 256 * 2);
  unsigned short* encb  = (unsigned short*)alloc((size_t)NN * 256 * 2);
  unsigned short* W1t   = (unsigned short*)alloc(512 * 256 * 2);
  unsigned short* W2t   = (unsigned short*)alloc(512 * 256 * 2);
  unsigned short* W34t  = (unsigned short*)alloc(512 * 256 * 2);
  float*          b34v  = (float*)alloc(512 * 4);
  int*            cnt   = (int*)alloc(NN * 4);
  int*            row_ptr = (int*)alloc((NN + 1) * 4);
  int*            fill  = (int*)alloc(NN * 4);
  int*            slist = (int*)alloc((size_t)EE * 4);
  float*          wlist = (float*)alloc((size_t)EE * 4);
  double*         sums  = (double*)alloc(32);  // [0]=kl, [1]=sp_sum, [2]=adj_dot

  float* out_enc2 = (float*)d_out;
  float* out_Z    = out_enc2 + (size_t)NN * 256;
  float* out_loss = out_Z + (size_t)NN * 8 * 256;

  hipMemsetAsync(cnt, 0, NN * 4, stream);
  hipMemsetAsync(fill, 0, NN * 4, stream);
  hipMemsetAsync(sums, 0, 32, stream);

  k_prep<<<2048, 256, 0, stream>>>(enc, W1, W2, W3, W4, b3, b4, encb, W1t, W2t, W34t, b34v);
  k_count<<<EE / 256, 256, 0, stream>>>(dst, cnt);
  k_scan<<<1, 1024, 0, stream>>>(cnt, row_ptr);
  k_fill<<<EE / 256, 256, 0, stream>>>(dst, src, w, row_ptr, fill, slist, wlist);

  // conv1 + block1 (gemm1 emits bf16 only)
  k_conv<<<NN / 4, 256, 0, stream>>>(encb, slist, wlist, row_ptr, h1b);
  k_gemm<true, false, false, true><<<dim3(64, 2), 256, 0, stream>>>(h1b, W1t, b1, nullptr, nullptr, hb, 512, 256);
  // conv2 + block2 (+ residual enc), f32 enc2 output + bf16 enc2
  k_conv<<<NN / 4, 256, 0, stream>>>(hb, slist, wlist, row_ptr, h1b);
  k_gemm<true, true, true, true><<<dim3(64, 2), 256, 0, stream>>>(h1b, W2t, b2, enc, out_enc2, enc2b, 512, 256);
  // mu|lv fused GEMM
  k_gemm<false, false, true, false><<<dim3(64, 4), 256, 0, stream>>>(enc2b, W34t, b34v, nullptr, mulv, nullptr, 256, 512);
  // Z, Z_l, KL
  k_z<<<NN / 4, 256, 0, stream>>>(mulv, eps, out_Z, Zlb, sums);
  // graph loss: softplus term (triangular, no ADJ) + sparse adj-dot term (BW-bound)
  k_adj<<<NN / 4, 256, 0, stream>>>(ADJ, Zlb, sums + 2);
  k_logits<<<dim3(64, 64), 256, 0, stream>>>(Zlb, sums + 1);
  k_final<<<1, 1, 0, stream>>>(sums, out_loss);
}